// Round 1
// 749.382 us; speedup vs baseline: 1.0436x; 1.0436x over previous
//
#include <hip/hip_runtime.h>
#include <hip/hip_bf16.h>
#include <type_traits>

typedef __attribute__((ext_vector_type(8))) __bf16 bf16x8;
typedef __attribute__((ext_vector_type(4))) float f32x4;
typedef unsigned short u16;

__device__ __forceinline__ u16 f2b(float x) {
  union { __hip_bfloat16 b; u16 u; } cv;
  cv.b = __float2bfloat16(x);
  return cv.u;
}

// async global->LDS, 16 B per lane. LDS dst = wave-uniform base + lane*16.
__device__ __forceinline__ void ld16(const u16* g, u16* l) {
  __builtin_amdgcn_global_load_lds(
      (const __attribute__((address_space(1))) unsigned int*)g,
      (__attribute__((address_space(3))) unsigned int*)l, 16, 0, 0);
}

// 256x256 tile, BK=64, 512 threads = 8 waves (2M x 4N), 128x64 out per wave.
// LDS: 2 x (A 32KB + B 32KB) = 128KB double buffer -> 1 block/CU, 2 waves/SIMD.
// Swizzle (verified, SQ_LDS_BANK_CONFLICT=0): row r stores global 16B-chunk
// c at slot c^(r&7); staging permutes the per-lane GLOBAL source column since
// global_load_lds pins LDS dst to base + lane*16. Read back with the same XOR.
constexpr int BM = 256, BN = 256, BK = 64;

enum { EPI_NONE = 0, EPI_BIAS = 1, EPI_BIAS_T = 2, EPI_MASK = 3 };

// One phase: quadrant (QR,QC) of the wave's 128x64 tile, full K=64.
// LA/LB: load fresh A/B fragments (Gray-code order reuses the other operand).
// Template: reads -> s_barrier -> (auto lgkmcnt) -> setprio(1) 16xMFMA -> bar.
#define PHASE(QR, QC, LA, LB, BUF)                                            \
  {                                                                           \
    if (LA) {                                                                 \
      _Pragma("unroll") for (int i = 0; i < 4; ++i)                           \
          _Pragma("unroll") for (int ks = 0; ks < 2; ++ks)                    \
              aF[i][ks] = *(const bf16x8*)&As[BUF][                           \
                  (wr * 128 + QR * 64 + i * 16 + fr) * BK +                   \
                  (((ks * 4 + quad) ^ (fr & 7)) * 8)];                        \
    }                                                                         \
    if (LB) {                                                                 \
      _Pragma("unroll") for (int j = 0; j < 2; ++j)                           \
          _Pragma("unroll") for (int ks = 0; ks < 2; ++ks)                    \
              bF[j][ks] = *(const bf16x8*)&Bs[BUF][                           \
                  (wc * 64 + QC * 32 + j * 16 + fr) * BK +                    \
                  (((ks * 4 + quad) ^ (fr & 7)) * 8)];                        \
    }                                                                         \
    __builtin_amdgcn_s_barrier();                                             \
    __builtin_amdgcn_s_setprio(1);                                            \
    _Pragma("unroll") for (int i = 0; i < 4; ++i)                             \
        _Pragma("unroll") for (int j = 0; j < 2; ++j)                         \
            _Pragma("unroll") for (int ks = 0; ks < 2; ++ks)                  \
                acc[QR * 4 + i][QC * 2 + j] =                                 \
                    __builtin_amdgcn_mfma_f32_16x16x32_bf16(                  \
                        aF[i][ks], bF[j][ks], acc[QR * 4 + i][QC * 2 + j],    \
                        0, 0, 0);                                             \
    __builtin_amdgcn_s_setprio(0);                                            \
    __builtin_amdgcn_s_barrier();                                             \
  }

// C[m,n] = sum_k A[m,k] * Bt[n,k] (+ epilogue). A,Bt bf16.
// EPI_BIAS_T: C = Vt [8][1024][2048] bf16, written transposed (seq=2048).
template <typename TC, int EPI>
__global__ __launch_bounds__(512, 2) void gemm_bt(
    const u16* __restrict__ A, const u16* __restrict__ Bt, TC* __restrict__ C,
    const float* __restrict__ bias, const int* __restrict__ mask, float scale,
    int N, int K, long long sA, long long sB, long long sC, long long sM) {
  __shared__ u16 As[2][BM * BK];  // 2 x 32 KB
  __shared__ u16 Bs[2][BN * BK];  // 2 x 32 KB

  const int bz = blockIdx.z;
  A += (size_t)bz * sA;
  Bt += (size_t)bz * sB;
  C += (size_t)bz * sC;
  const long long maskBase = (long long)bz * sM;

  const int m0 = blockIdx.y * BM, n0 = blockIdx.x * BN;
  const int t = threadIdx.x, wave = t >> 6, lane = t & 63;
  const int wr = wave >> 2, wc = wave & 3;          // wave -> (M half, N quarter)
  const int fr = lane & 15, quad = lane >> 4;       // MFMA fragment coords
  const int lr = lane >> 3, lc = lane & 7;          // staging coords

  // staging: wave w, issue i covers rows i*64 + w*8 + lr; source col chunk
  // pre-swizzled (lc^lr) so linear LDS dst realizes slot = chunk ^ (row&7).
  const u16* ga = A + (size_t)(m0 + wave * 8 + lr) * K + (lc ^ lr) * 8;
  const u16* gb = Bt + (size_t)(n0 + wave * 8 + lr) * K + (lc ^ lr) * 8;

  f32x4 acc[8][4] = {};
  bf16x8 aF[4][2], bF[2][2];

  const int nt = K / BK;

  auto STAGE = [&](int kt, int bsel) {
    const size_t ko = (size_t)kt * BK;
#pragma unroll
    for (int i = 0; i < 4; ++i) {
      ld16(ga + (size_t)(i * 64) * K + ko,
           &As[bsel][(i * 64 + wave * 8) * BK]);
      ld16(gb + (size_t)(i * 64) * K + ko,
           &Bs[bsel][(i * 64 + wave * 8) * BK]);
    }
  };

  // depth-2 prologue: 16 loads/thread in flight.
  STAGE(0, 0);
  STAGE(1, 1);

  for (int kt = 0; kt < nt; ++kt) {
    const int b = kt & 1;
    // counted wait: outstanding = S(kt) 8 + S(kt+1) 8 -> vmcnt(8) lands S(kt).
    // Only the final tile (nothing newer in flight) drains to 0.
    if (kt + 1 < nt)
      __builtin_amdgcn_s_waitcnt(0x0f78);  // vmcnt(8)
    else
      __builtin_amdgcn_s_waitcnt(0x0f70);  // vmcnt(0)
    __builtin_amdgcn_s_barrier();          // S(kt) visible block-wide
    __builtin_amdgcn_sched_barrier(0);

    // Gray-code quadrants: reuse A across (0,0)->(0,1), B across (0,1)->(1,1).
    PHASE(0, 0, 1, 1, b)
    PHASE(0, 1, 0, 1, b)
    PHASE(1, 1, 1, 0, b)
    PHASE(1, 0, 0, 1, b)

    // After the last phase's trailing barrier every wave's reads of buf b are
    // complete -> safe to overwrite it with tile kt+2 (issue-to-use distance
    // = one full tile body, covers ~900cy HBM latency).
    __builtin_amdgcn_sched_barrier(0);
    if (kt + 2 < nt) STAGE(kt + 2, b);
  }

  // C/D layout: col = lane&15 (fr), row = quad*4 + reg
#pragma unroll
  for (int i = 0; i < 8; ++i)
#pragma unroll
    for (int j = 0; j < 4; ++j) {
      const int mb = m0 + wr * 128 + i * 16 + quad * 4;
      const int n = n0 + wc * 64 + j * 16 + fr;
      if constexpr (EPI == EPI_BIAS_T) {
        const float bb = bias[n];
        const int b = mb >> 11, ml = mb & 2047;  // seq = 2048 per batch
        ushort4 o;
        o.x = f2b(acc[i][j][0] + bb);
        o.y = f2b(acc[i][j][1] + bb);
        o.z = f2b(acc[i][j][2] + bb);
        o.w = f2b(acc[i][j][3] + bb);
        *(ushort4*)&((u16*)C)[(size_t)b * 2097152 + (size_t)n * 2048 + ml] = o;
      } else {
#pragma unroll
        for (int r = 0; r < 4; ++r) {
          const int m = mb + r;
          float v = acc[i][j][r];
          if constexpr (EPI == EPI_BIAS) v += bias[n];
          if constexpr (EPI == EPI_MASK)
            v = mask[maskBase + (size_t)m * N + n] ? -1e9f : v * scale;
          if constexpr (std::is_same_v<TC, u16>)
            C[(size_t)m * N + n] = f2b(v);
          else
            C[(size_t)m * N + n] = v;
        }
      }
    }
}

// ---------------------------------------------------------------------------
// fp32 -> bf16 casts for x, ctx, Wq, Wk, Wv in one 1-D launch.
// blocks: [0,16384) x, [16384,32768) ctx, then 3x1024 for the weights.
// ---------------------------------------------------------------------------
__global__ __launch_bounds__(256) void cast_all(
    const float* __restrict__ x, const float* __restrict__ ctx,
    const float* __restrict__ wq, const float* __restrict__ wk,
    const float* __restrict__ wv, u16* __restrict__ xb, u16* __restrict__ cb,
    u16* __restrict__ wqb, u16* __restrict__ wkb, u16* __restrict__ wvb) {
  int b = blockIdx.x;
  const float* s;
  u16* d;
  size_t off;
  if (b < 16384) { s = x; d = xb; off = b; }
  else if (b < 32768) { s = ctx; d = cb; off = b - 32768 + 16384; }
  else if (b < 33792) { s = wq; d = wqb; off = b - 32768; }
  else if (b < 34816) { s = wk; d = wkb; off = b - 33792; }
  else { s = wv; d = wvb; off = b - 34816; }
  const size_t i = (off * 256 + threadIdx.x) * 4;
  float4 v = *(const float4*)&s[i];
  ushort4 h;
  h.x = f2b(v.x); h.y = f2b(v.y); h.z = f2b(v.z); h.w = f2b(v.w);
  *(ushort4*)&d[i] = h;
}

// ---------------------------------------------------------------------------
// In-place row softmax over att [16384][2048] fp32 + bf16 copy for AV GEMM.
// ---------------------------------------------------------------------------
__device__ __forceinline__ float blockReduceMax(float v, float* red) {
#pragma unroll
  for (int o = 32; o > 0; o >>= 1) v = fmaxf(v, __shfl_down(v, o));
  int t = threadIdx.x;
  if ((t & 63) == 0) red[t >> 6] = v;
  __syncthreads();
  float r = fmaxf(fmaxf(red[0], red[1]), fmaxf(red[2], red[3]));
  __syncthreads();
  return r;
}

__device__ __forceinline__ float blockReduceSum(float v, float* red) {
#pragma unroll
  for (int o = 32; o > 0; o >>= 1) v += __shfl_down(v, o);
  int t = threadIdx.x;
  if ((t & 63) == 0) red[t >> 6] = v;
  __syncthreads();
  float r = red[0] + red[1] + red[2] + red[3];
  __syncthreads();
  return r;
}

__global__ __launch_bounds__(256) void softmax_rows(float* __restrict__ att,
                                                    u16* __restrict__ attb) {
  __shared__ float red[4];
  float* p = att + (size_t)blockIdx.x * 2048;
  u16* pb = attb + (size_t)blockIdx.x * 2048;
  const int t = threadIdx.x;
  float4 v0 = ((const float4*)p)[t];
  float4 v1 = ((const float4*)p)[t + 256];
  float mx = fmaxf(fmaxf(fmaxf(v0.x, v0.y), fmaxf(v0.z, v0.w)),
                   fmaxf(fmaxf(v1.x, v1.y), fmaxf(v1.z, v1.w)));
  mx = blockReduceMax(mx, red);
  float4 e0, e1;
  e0.x = __expf(v0.x - mx); e0.y = __expf(v0.y - mx);
  e0.z = __expf(v0.z - mx); e0.w = __expf(v0.w - mx);
  e1.x = __expf(v1.x - mx); e1.y = __expf(v1.y - mx);
  e1.z = __expf(v1.z - mx); e1.w = __expf(v1.w - mx);
  float s = (e0.x + e0.y + e0.z + e0.w) + (e1.x + e1.y + e1.z + e1.w);
  s = blockReduceSum(s, red);
  float inv = 1.0f / s;
  e0.x *= inv; e0.y *= inv; e0.z *= inv; e0.w *= inv;
  e1.x *= inv; e1.y *= inv; e1.z *= inv; e1.w *= inv;
  ((float4*)p)[t] = e0;
  ((float4*)p)[t + 256] = e1;
  ushort4 h0, h1;
  h0.x = f2b(e0.x); h0.y = f2b(e0.y); h0.z = f2b(e0.z); h0.w = f2b(e0.w);
  h1.x = f2b(e1.x); h1.y = f2b(e1.y); h1.z = f2b(e1.z); h1.w = f2b(e1.w);
  *(ushort4*)&pb[(size_t)t * 4] = h0;
  *(ushort4*)&pb[(size_t)(t + 256) * 4] = h1;
}

// ---------------------------------------------------------------------------
extern "C" void kernel_launch(void* const* d_in, const int* in_sizes, int n_in,
                              void* d_out, int out_size, void* d_ws,
                              size_t ws_size, hipStream_t stream) {
  const float* x   = (const float*)d_in[0];  // [8,2048,1024]
  const float* ctx = (const float*)d_in[1];  // [8,2048,1024]
  const int*   msk = (const int*)d_in[2];    // [8,2048,2048]
  const float* Wq  = (const float*)d_in[3];  // [1024,1024] == B^T layout
  const float* bq  = (const float*)d_in[4];
  const float* Wk  = (const float*)d_in[5];
  const float* bk  = (const float*)d_in[6];
  const float* Wv  = (const float*)d_in[7];
  const float* bv  = (const float*)d_in[8];

  float* out = (float*)d_out;   // 8*2048*1024
  float* att = out + 16777216;  // 8*2048*2048

  // ws (134 MB): xb | cb | Q | Kb.  Aliases: Vt<-xb (dead after Q proj),
  // attb<-Q+Kb (dead after QK^T).
  u16* xb = (u16*)d_ws;
  u16* cb = xb + 16777216;
  u16* Q  = cb + 16777216;
  u16* Kb = Q + 16777216;
  u16* Vt = xb;
  u16* attb = Q;
  // bf16 weights live in the att region of d_out; dead before QK^T writes it.
  u16* wqb = (u16*)att;
  u16* wkb = wqb + 1048576;
  u16* wvb = wkb + 1048576;

  dim3 blk(256), blkg(512);
  const long long SQ = 2048LL * 1024, SS = 2048LL * 2048, SV = 1024LL * 2048;

  cast_all<<<dim3(35840), blk, 0, stream>>>(x, ctx, Wq, Wk, Wv, xb, cb, wqb,
                                            wkb, wvb);

  // projections: M=16384, N=1024, K=1024 (Q first: V overwrites xb region)
  gemm_bt<u16, EPI_BIAS><<<dim3(4, 64, 1), blkg, 0, stream>>>(
      xb, wqb, Q, bq, nullptr, 0.f, 1024, 1024, 0, 0, 0, 0);
  gemm_bt<u16, EPI_BIAS><<<dim3(4, 64, 1), blkg, 0, stream>>>(
      cb, wkb, Kb, bk, nullptr, 0.f, 1024, 1024, 0, 0, 0, 0);
  gemm_bt<u16, EPI_BIAS_T><<<dim3(4, 64, 1), blkg, 0, stream>>>(
      cb, wvb, Vt, bv, nullptr, 0.f, 1024, 1024, 0, 0, 0, 0);

  // logits = Q K^T * scale, masked -> att (fp32, overwrites weight scratch)
  gemm_bt<float, EPI_MASK><<<dim3(8, 8, 8), blkg, 0, stream>>>(
      Q, Kb, att, nullptr, msk, 0.03125f, 2048, 1024, SQ, SQ, SS, SS);

  softmax_rows<<<dim3(16384), blk, 0, stream>>>(att, attb);

  // out = att @ V : A=attb bf16, Bt=Vt bf16
  gemm_bt<float, EPI_NONE><<<dim3(4, 8, 8), blkg, 0, stream>>>(
      attb, Vt, out, nullptr, nullptr, 0.f, 1024, 2048, SS, SV, SQ, 0);
}

// Round 2
// 696.938 us; speedup vs baseline: 1.1221x; 1.0752x over previous
//
#include <hip/hip_runtime.h>
#include <hip/hip_bf16.h>
#include <type_traits>

typedef __attribute__((ext_vector_type(8))) __bf16 bf16x8;
typedef __attribute__((ext_vector_type(4))) float f32x4;
typedef unsigned short u16;

__device__ __forceinline__ u16 f2b(float x) {
  union { __hip_bfloat16 b; u16 u; } cv;
  cv.b = __float2bfloat16(x);
  return cv.u;
}

// async global->LDS, 16 B per lane. LDS dst = wave-uniform base + lane*16.
__device__ __forceinline__ void ld16(const u16* g, u16* l) {
  __builtin_amdgcn_global_load_lds(
      (const __attribute__((address_space(1))) unsigned int*)g,
      (__attribute__((address_space(3))) unsigned int*)l, 16, 0, 0);
}

// 256x256 tile, BK=64, 512 threads = 8 waves (2M x 4N), 128x64 out per wave.
// LDS: 2 x (A 32KB + B 32KB) = 128KB double buffer -> 1 block/CU, 2 waves/SIMD.
// Swizzle (verified, SQ_LDS_BANK_CONFLICT=0): row r stores global 16B-chunk
// c at slot c^(r&7); staging permutes the per-lane GLOBAL source column since
// global_load_lds pins LDS dst to base + lane*16. Read back with the same XOR.
//
// Schedule: FREE-RUNNING tile body. Only 2 barriers per K-tile:
//   entry:  own vmcnt(8) -> s_barrier  => S(kt) visible block-wide
//   exit:   s_barrier -> STAGE(kt+2)   => all reads of buf b done before reuse
// No intra-tile barriers: nothing writes LDS inside a tile, so waves drift and
// one wave's ds_reads hide under the other SIMD-resident wave's MFMAs (m114).
constexpr int BM = 256, BN = 256, BK = 64;

enum { EPI_NONE = 0, EPI_BIAS = 1, EPI_BIAS_T = 2 };

// One phase: quadrant (QR,QC) of the wave's 128x64 tile, full K=64.
// LA/LB: load fresh A/B fragments (Gray-code order reuses the other operand).
#define PHASE(QR, QC, LA, LB, BUF)                                            \
  {                                                                           \
    if (LA) {                                                                 \
      _Pragma("unroll") for (int i = 0; i < 4; ++i)                           \
          _Pragma("unroll") for (int ks = 0; ks < 2; ++ks)                    \
              aF[i][ks] = *(const bf16x8*)&As[BUF][                           \
                  (wr * 128 + QR * 64 + i * 16 + fr) * BK +                   \
                  (((ks * 4 + quad) ^ (fr & 7)) * 8)];                        \
    }                                                                         \
    if (LB) {                                                                 \
      _Pragma("unroll") for (int j = 0; j < 2; ++j)                           \
          _Pragma("unroll") for (int ks = 0; ks < 2; ++ks)                    \
              bF[j][ks] = *(const bf16x8*)&Bs[BUF][                           \
                  (wc * 64 + QC * 32 + j * 16 + fr) * BK +                    \
                  (((ks * 4 + quad) ^ (fr & 7)) * 8)];                        \
    }                                                                         \
    _Pragma("unroll") for (int i = 0; i < 4; ++i)                             \
        _Pragma("unroll") for (int j = 0; j < 2; ++j)                         \
            _Pragma("unroll") for (int ks = 0; ks < 2; ++ks)                  \
                acc[QR * 4 + i][QC * 2 + j] =                                 \
                    __builtin_amdgcn_mfma_f32_16x16x32_bf16(                  \
                        aF[i][ks], bF[j][ks], acc[QR * 4 + i][QC * 2 + j],    \
                        0, 0, 0);                                             \
  }

// C[m,n] = sum_k A[m,k] * Bt[n,k] (+ epilogue). A,Bt bf16.
// EPI_BIAS_T: C = Vt [8][1024][2048] bf16, written transposed (seq=2048).
template <typename TC, int EPI>
__global__ __launch_bounds__(512, 2) void gemm_bt(
    const u16* __restrict__ A, const u16* __restrict__ Bt, TC* __restrict__ C,
    const float* __restrict__ bias, float scale, int N, int K, long long sA,
    long long sB, long long sC) {
  __shared__ u16 As[2][BM * BK];  // 2 x 32 KB
  __shared__ u16 Bs[2][BN * BK];  // 2 x 32 KB

  const int bz = blockIdx.z;
  A += (size_t)bz * sA;
  Bt += (size_t)bz * sB;
  C += (size_t)bz * sC;

  const int m0 = blockIdx.y * BM, n0 = blockIdx.x * BN;
  const int t = threadIdx.x, wave = t >> 6, lane = t & 63;
  const int wr = wave >> 2, wc = wave & 3;          // wave -> (M half, N quarter)
  const int fr = lane & 15, quad = lane >> 4;       // MFMA fragment coords
  const int lr = lane >> 3, lc = lane & 7;          // staging coords

  // staging: wave w, issue i covers rows i*64 + w*8 + lr; source col chunk
  // pre-swizzled (lc^lr) so linear LDS dst realizes slot = chunk ^ (row&7).
  const u16* ga = A + (size_t)(m0 + wave * 8 + lr) * K + (lc ^ lr) * 8;
  const u16* gb = Bt + (size_t)(n0 + wave * 8 + lr) * K + (lc ^ lr) * 8;

  f32x4 acc[8][4] = {};
  bf16x8 aF[4][2], bF[2][2];

  const int nt = K / BK;

  auto STAGE = [&](int kt, int bsel) {
    const size_t ko = (size_t)kt * BK;
#pragma unroll
    for (int i = 0; i < 4; ++i) {
      ld16(ga + (size_t)(i * 64) * K + ko,
           &As[bsel][(i * 64 + wave * 8) * BK]);
      ld16(gb + (size_t)(i * 64) * K + ko,
           &Bs[bsel][(i * 64 + wave * 8) * BK]);
    }
  };

  // depth-2 prologue: 16 loads/thread in flight.
  STAGE(0, 0);
  STAGE(1, 1);

  for (int kt = 0; kt < nt; ++kt) {
    const int b = kt & 1;
    // counted wait: outstanding = S(kt) 8 + S(kt+1) 8 -> vmcnt(8) lands S(kt).
    // Only the final tile (nothing newer in flight) drains to 0.
    if (kt + 1 < nt)
      __builtin_amdgcn_s_waitcnt(0x0f78);  // vmcnt(8)
    else
      __builtin_amdgcn_s_waitcnt(0x0f70);  // vmcnt(0)
    __builtin_amdgcn_s_barrier();          // S(kt) visible block-wide
    __builtin_amdgcn_sched_barrier(0);     // keep tile reads below the barrier

    // Gray-code quadrants: reuse A across (0,0)->(0,1), B across (0,1)->(1,1).
    // No barriers inside: compiler/HW interleave ds_read and MFMA freely.
    PHASE(0, 0, 1, 1, b)
    PHASE(0, 1, 0, 1, b)
    PHASE(1, 1, 1, 0, b)
    PHASE(1, 0, 0, 1, b)

    // All waves must finish reading buf b before it is restaged.
    __builtin_amdgcn_sched_barrier(0);
    __builtin_amdgcn_s_barrier();
    if (kt + 2 < nt) STAGE(kt + 2, b);
  }

  // C/D layout: col = lane&15 (fr), row = quad*4 + reg
#pragma unroll
  for (int i = 0; i < 8; ++i)
#pragma unroll
    for (int j = 0; j < 4; ++j) {
      const int mb = m0 + wr * 128 + i * 16 + quad * 4;
      const int n = n0 + wc * 64 + j * 16 + fr;
      if constexpr (EPI == EPI_BIAS_T) {
        const float bb = bias[n];
        const int b = mb >> 11, ml = mb & 2047;  // seq = 2048 per batch
        ushort4 o;
        o.x = f2b(acc[i][j][0] + bb);
        o.y = f2b(acc[i][j][1] + bb);
        o.z = f2b(acc[i][j][2] + bb);
        o.w = f2b(acc[i][j][3] + bb);
        *(ushort4*)&((u16*)C)[(size_t)b * 2097152 + (size_t)n * 2048 + ml] = o;
      } else {
#pragma unroll
        for (int r = 0; r < 4; ++r) {
          const int m = mb + r;
          float v = acc[i][j][r];
          if constexpr (EPI == EPI_BIAS) v += bias[n];
          if constexpr (std::is_same_v<TC, u16>)
            C[(size_t)m * N + n] = f2b(v);
          else
            C[(size_t)m * N + n] = v;
        }
      }
    }
}

// ---------------------------------------------------------------------------
// fp32 -> bf16 casts for x, ctx, Wq, Wk, Wv in one 1-D launch.
// blocks: [0,16384) x, [16384,32768) ctx, then 3x1024 for the weights.
// ---------------------------------------------------------------------------
__global__ __launch_bounds__(256) void cast_all(
    const float* __restrict__ x, const float* __restrict__ ctx,
    const float* __restrict__ wq, const float* __restrict__ wk,
    const float* __restrict__ wv, u16* __restrict__ xb, u16* __restrict__ cb,
    u16* __restrict__ wqb, u16* __restrict__ wkb, u16* __restrict__ wvb) {
  int b = blockIdx.x;
  const float* s;
  u16* d;
  size_t off;
  if (b < 16384) { s = x; d = xb; off = b; }
  else if (b < 32768) { s = ctx; d = cb; off = b - 32768 + 16384; }
  else if (b < 33792) { s = wq; d = wqb; off = b - 32768; }
  else if (b < 34816) { s = wk; d = wkb; off = b - 33792; }
  else { s = wv; d = wvb; off = b - 34816; }
  const size_t i = (off * 256 + threadIdx.x) * 4;
  float4 v = *(const float4*)&s[i];
  ushort4 h;
  h.x = f2b(v.x); h.y = f2b(v.y); h.z = f2b(v.z); h.w = f2b(v.w);
  *(ushort4*)&d[i] = h;
}

// ---------------------------------------------------------------------------
// Row softmax over att [16384][2048]: reads RAW logits (fp32), applies
// scale + pad-mask (-1e9), softmax, writes fp32 att in place + bf16 copy.
// Fully-masked rows -> all -1e9 -> exp(0)=1 each -> uniform (matches ref).
// ---------------------------------------------------------------------------
__device__ __forceinline__ float blockReduceMax(float v, float* red) {
#pragma unroll
  for (int o = 32; o > 0; o >>= 1) v = fmaxf(v, __shfl_down(v, o));
  int t = threadIdx.x;
  if ((t & 63) == 0) red[t >> 6] = v;
  __syncthreads();
  float r = fmaxf(fmaxf(red[0], red[1]), fmaxf(red[2], red[3]));
  __syncthreads();
  return r;
}

__device__ __forceinline__ float blockReduceSum(float v, float* red) {
#pragma unroll
  for (int o = 32; o > 0; o >>= 1) v += __shfl_down(v, o);
  int t = threadIdx.x;
  if ((t & 63) == 0) red[t >> 6] = v;
  __syncthreads();
  float r = red[0] + red[1] + red[2] + red[3];
  __syncthreads();
  return r;
}

__global__ __launch_bounds__(256) void softmax_rows(float* __restrict__ att,
                                                    u16* __restrict__ attb,
                                                    const int* __restrict__ msk,
                                                    float scale) {
  __shared__ float red[4];
  float* p = att + (size_t)blockIdx.x * 2048;
  const int* mr = msk + (size_t)blockIdx.x * 2048;
  u16* pb = attb + (size_t)blockIdx.x * 2048;
  const int t = threadIdx.x;
  float4 v0 = ((const float4*)p)[t];
  float4 v1 = ((const float4*)p)[t + 256];
  int4 q0 = ((const int4*)mr)[t];
  int4 q1 = ((const int4*)mr)[t + 256];
  v0.x = q0.x ? -1e9f : v0.x * scale;
  v0.y = q0.y ? -1e9f : v0.y * scale;
  v0.z = q0.z ? -1e9f : v0.z * scale;
  v0.w = q0.w ? -1e9f : v0.w * scale;
  v1.x = q1.x ? -1e9f : v1.x * scale;
  v1.y = q1.y ? -1e9f : v1.y * scale;
  v1.z = q1.z ? -1e9f : v1.z * scale;
  v1.w = q1.w ? -1e9f : v1.w * scale;
  float mx = fmaxf(fmaxf(fmaxf(v0.x, v0.y), fmaxf(v0.z, v0.w)),
                   fmaxf(fmaxf(v1.x, v1.y), fmaxf(v1.z, v1.w)));
  mx = blockReduceMax(mx, red);
  float4 e0, e1;
  e0.x = __expf(v0.x - mx); e0.y = __expf(v0.y - mx);
  e0.z = __expf(v0.z - mx); e0.w = __expf(v0.w - mx);
  e1.x = __expf(v1.x - mx); e1.y = __expf(v1.y - mx);
  e1.z = __expf(v1.z - mx); e1.w = __expf(v1.w - mx);
  float s = (e0.x + e0.y + e0.z + e0.w) + (e1.x + e1.y + e1.z + e1.w);
  s = blockReduceSum(s, red);
  float inv = 1.0f / s;
  e0.x *= inv; e0.y *= inv; e0.z *= inv; e0.w *= inv;
  e1.x *= inv; e1.y *= inv; e1.z *= inv; e1.w *= inv;
  ((float4*)p)[t] = e0;
  ((float4*)p)[t + 256] = e1;
  ushort4 h0, h1;
  h0.x = f2b(e0.x); h0.y = f2b(e0.y); h0.z = f2b(e0.z); h0.w = f2b(e0.w);
  h1.x = f2b(e1.x); h1.y = f2b(e1.y); h1.z = f2b(e1.z); h1.w = f2b(e1.w);
  *(ushort4*)&pb[(size_t)t * 4] = h0;
  *(ushort4*)&pb[(size_t)(t + 256) * 4] = h1;
}

// ---------------------------------------------------------------------------
extern "C" void kernel_launch(void* const* d_in, const int* in_sizes, int n_in,
                              void* d_out, int out_size, void* d_ws,
                              size_t ws_size, hipStream_t stream) {
  const float* x   = (const float*)d_in[0];  // [8,2048,1024]
  const float* ctx = (const float*)d_in[1];  // [8,2048,1024]
  const int*   msk = (const int*)d_in[2];    // [8,2048,2048]
  const float* Wq  = (const float*)d_in[3];  // [1024,1024] == B^T layout
  const float* bq  = (const float*)d_in[4];
  const float* Wk  = (const float*)d_in[5];
  const float* bk  = (const float*)d_in[6];
  const float* Wv  = (const float*)d_in[7];
  const float* bv  = (const float*)d_in[8];

  float* out = (float*)d_out;   // 8*2048*1024
  float* att = out + 16777216;  // 8*2048*2048

  // ws (134 MB): xb | cb | Q | Kb.  Aliases: Vt<-xb (dead after Q proj),
  // attb<-Q+Kb (dead after QK^T).
  u16* xb = (u16*)d_ws;
  u16* cb = xb + 16777216;
  u16* Q  = cb + 16777216;
  u16* Kb = Q + 16777216;
  u16* Vt = xb;
  u16* attb = Q;
  // bf16 weights live in the att region of d_out; dead before QK^T writes it.
  u16* wqb = (u16*)att;
  u16* wkb = wqb + 1048576;
  u16* wvb = wkb + 1048576;

  dim3 blk(256), blkg(512);
  const long long SQ = 2048LL * 1024, SS = 2048LL * 2048, SV = 1024LL * 2048;

  cast_all<<<dim3(35840), blk, 0, stream>>>(x, ctx, Wq, Wk, Wv, xb, cb, wqb,
                                            wkb, wvb);

  // projections: M=16384, N=1024, K=1024 (Q first: V overwrites xb region)
  gemm_bt<u16, EPI_BIAS><<<dim3(4, 64, 1), blkg, 0, stream>>>(
      xb, wqb, Q, bq, 0.f, 1024, 1024, 0, 0, 0);
  gemm_bt<u16, EPI_BIAS><<<dim3(4, 64, 1), blkg, 0, stream>>>(
      cb, wkb, Kb, bk, 0.f, 1024, 1024, 0, 0, 0);
  gemm_bt<u16, EPI_BIAS_T><<<dim3(4, 64, 1), blkg, 0, stream>>>(
      cb, wvb, Vt, bv, 0.f, 1024, 1024, 0, 0, 0);

  // logits = Q K^T (RAW, fp32) -> att; scale+mask applied in softmax_rows
  gemm_bt<float, EPI_NONE><<<dim3(8, 8, 8), blkg, 0, stream>>>(
      Q, Kb, att, nullptr, 0.f, 2048, 1024, SQ, SQ, SS);

  softmax_rows<<<dim3(16384), blk, 0, stream>>>(att, attb, msk, 0.03125f);

  // out = att @ V : A=attb bf16, Bt=Vt bf16
  gemm_bt<float, EPI_NONE><<<dim3(4, 8, 8), blkg, 0, stream>>>(
      attb, Vt, out, nullptr, 0.f, 1024, 2048, SS, SV, SQ);
}

// Round 3
// 682.238 us; speedup vs baseline: 1.1463x; 1.0215x over previous
//
#include <hip/hip_runtime.h>
#include <hip/hip_bf16.h>
#include <type_traits>

typedef __attribute__((ext_vector_type(8))) __bf16 bf16x8;
typedef __attribute__((ext_vector_type(4))) float f32x4;
typedef unsigned short u16;

__device__ __forceinline__ u16 f2b(float x) {
  union { __hip_bfloat16 b; u16 u; } cv;
  cv.b = __float2bfloat16(x);
  return cv.u;
}

// async global->LDS, 16 B per lane. LDS dst = wave-uniform base + lane*16.
__device__ __forceinline__ void ld16(const u16* g, u16* l) {
  __builtin_amdgcn_global_load_lds(
      (const __attribute__((address_space(1))) unsigned int*)g,
      (__attribute__((address_space(3))) unsigned int*)l, 16, 0, 0);
}

// 256x256 tile, BK=64, 512 threads = 8 waves (2M x 4N), 128x64 out per wave.
// LDS: 2 x (A 32KB + B 32KB) = 128KB double buffer -> 1 block/CU, 2 waves/SIMD.
// Swizzle (verified, SQ_LDS_BANK_CONFLICT=0): row r stores global 16B-chunk
// c at slot c^(r&7); staging permutes the per-lane GLOBAL source column since
// global_load_lds pins LDS dst to base + lane*16. Read back with the same XOR.
//
// Schedule: free-running tile body, 2 barriers per K-tile (entry vmcnt(8)+bar,
// exit bar+restage). Round-2 diagnosis: the binding resource is HBM panel
// re-fetch (grid-x neighbors sharing an A panel land on different XCDs/L2s ->
// up to 8x amplification; QK^T measured 214 MB vs ~36 MB fundamental). Fix
// below: XCD-aware chunked remap of the flat block id (T1).
constexpr int BM = 256, BN = 256, BK = 64;

enum { EPI_NONE = 0, EPI_BIAS = 1, EPI_BIAS_T = 2 };

// One phase: quadrant (QR,QC) of the wave's 128x64 tile, full K=64.
// LA/LB: load fresh A/B fragments (Gray-code order reuses the other operand).
#define PHASE(QR, QC, LA, LB, BUF)                                            \
  {                                                                           \
    if (LA) {                                                                 \
      _Pragma("unroll") for (int i = 0; i < 4; ++i)                           \
          _Pragma("unroll") for (int ks = 0; ks < 2; ++ks)                    \
              aF[i][ks] = *(const bf16x8*)&As[BUF][                           \
                  (wr * 128 + QR * 64 + i * 16 + fr) * BK +                   \
                  (((ks * 4 + quad) ^ (fr & 7)) * 8)];                        \
    }                                                                         \
    if (LB) {                                                                 \
      _Pragma("unroll") for (int j = 0; j < 2; ++j)                           \
          _Pragma("unroll") for (int ks = 0; ks < 2; ++ks)                    \
              bF[j][ks] = *(const bf16x8*)&Bs[BUF][                           \
                  (wc * 64 + QC * 32 + j * 16 + fr) * BK +                    \
                  (((ks * 4 + quad) ^ (fr & 7)) * 8)];                        \
    }                                                                         \
    _Pragma("unroll") for (int i = 0; i < 4; ++i)                             \
        _Pragma("unroll") for (int j = 0; j < 2; ++j)                         \
            _Pragma("unroll") for (int ks = 0; ks < 2; ++ks)                  \
                acc[QR * 4 + i][QC * 2 + j] =                                 \
                    __builtin_amdgcn_mfma_f32_16x16x32_bf16(                  \
                        aF[i][ks], bF[j][ks], acc[QR * 4 + i][QC * 2 + j],    \
                        0, 0, 0);                                             \
  }

// C[m,n] = sum_k A[m,k] * Bt[n,k] (+ epilogue). A,Bt bf16.
// EPI_BIAS_T: C = Vt [8][1024][2048] bf16, written transposed (seq=2048).
template <typename TC, int EPI>
__global__ __launch_bounds__(512, 2) void gemm_bt(
    const u16* __restrict__ A, const u16* __restrict__ Bt, TC* __restrict__ C,
    const float* __restrict__ bias, float scale, int N, int K, long long sA,
    long long sB, long long sC) {
  __shared__ u16 As[2][BM * BK];  // 2 x 32 KB
  __shared__ u16 Bs[2][BN * BK];  // 2 x 32 KB

  // --- XCD-aware chunked remap (T1). Hardware runs flat block i on XCD i%8;
  // give each XCD one contiguous x-fastest chunk of logical tiles so every
  // block sharing an A/B panel co-resides in a single XCD's L2. All grids
  // here have nwg % 8 == 0, so this mapping is bijective.
  const int gx = gridDim.x, gy = gridDim.y;
  const int nwg = gx * gy * gridDim.z;
  int flat = (blockIdx.z * gy + blockIdx.y) * gx + blockIdx.x;
  flat = (flat & 7) * (nwg >> 3) + (flat >> 3);
  const int bx = flat % gx;
  const int rem = flat / gx;
  const int by = rem % gy;
  const int bz = rem / gy;

  A += (size_t)bz * sA;
  Bt += (size_t)bz * sB;
  C += (size_t)bz * sC;

  const int m0 = by * BM, n0 = bx * BN;
  const int t = threadIdx.x, wave = t >> 6, lane = t & 63;
  const int wr = wave >> 2, wc = wave & 3;          // wave -> (M half, N quarter)
  const int fr = lane & 15, quad = lane >> 4;       // MFMA fragment coords
  const int lr = lane >> 3, lc = lane & 7;          // staging coords

  // staging: wave w, issue i covers rows i*64 + w*8 + lr; source col chunk
  // pre-swizzled (lc^lr) so linear LDS dst realizes slot = chunk ^ (row&7).
  const u16* ga = A + (size_t)(m0 + wave * 8 + lr) * K + (lc ^ lr) * 8;
  const u16* gb = Bt + (size_t)(n0 + wave * 8 + lr) * K + (lc ^ lr) * 8;

  f32x4 acc[8][4] = {};
  bf16x8 aF[4][2], bF[2][2];

  const int nt = K / BK;

  auto STAGE = [&](int kt, int bsel) {
    const size_t ko = (size_t)kt * BK;
#pragma unroll
    for (int i = 0; i < 4; ++i) {
      ld16(ga + (size_t)(i * 64) * K + ko,
           &As[bsel][(i * 64 + wave * 8) * BK]);
      ld16(gb + (size_t)(i * 64) * K + ko,
           &Bs[bsel][(i * 64 + wave * 8) * BK]);
    }
  };

  // depth-2 prologue: 16 loads/thread in flight.
  STAGE(0, 0);
  STAGE(1, 1);

  for (int kt = 0; kt < nt; ++kt) {
    const int b = kt & 1;
    // counted wait: outstanding = S(kt) 8 + S(kt+1) 8 -> vmcnt(8) lands S(kt).
    // Only the final tile (nothing newer in flight) drains to 0.
    if (kt + 1 < nt)
      __builtin_amdgcn_s_waitcnt(0x0f78);  // vmcnt(8)
    else
      __builtin_amdgcn_s_waitcnt(0x0f70);  // vmcnt(0)
    __builtin_amdgcn_s_barrier();          // S(kt) visible block-wide
    __builtin_amdgcn_sched_barrier(0);     // keep tile reads below the barrier

    // Gray-code quadrants: reuse A across (0,0)->(0,1), B across (0,1)->(1,1).
    // No barriers inside: compiler/HW interleave ds_read and MFMA freely.
    PHASE(0, 0, 1, 1, b)
    PHASE(0, 1, 0, 1, b)
    PHASE(1, 1, 1, 0, b)
    PHASE(1, 0, 0, 1, b)

    // All waves must finish reading buf b before it is restaged.
    __builtin_amdgcn_sched_barrier(0);
    __builtin_amdgcn_s_barrier();
    if (kt + 2 < nt) STAGE(kt + 2, b);
  }

  // C/D layout: col = lane&15 (fr), row = quad*4 + reg
#pragma unroll
  for (int i = 0; i < 8; ++i)
#pragma unroll
    for (int j = 0; j < 4; ++j) {
      const int mb = m0 + wr * 128 + i * 16 + quad * 4;
      const int n = n0 + wc * 64 + j * 16 + fr;
      if constexpr (EPI == EPI_BIAS_T) {
        const float bb = bias[n];
        const int b = mb >> 11, ml = mb & 2047;  // seq = 2048 per batch
        ushort4 o;
        o.x = f2b(acc[i][j][0] + bb);
        o.y = f2b(acc[i][j][1] + bb);
        o.z = f2b(acc[i][j][2] + bb);
        o.w = f2b(acc[i][j][3] + bb);
        *(ushort4*)&((u16*)C)[(size_t)b * 2097152 + (size_t)n * 2048 + ml] = o;
      } else {
#pragma unroll
        for (int r = 0; r < 4; ++r) {
          const int m = mb + r;
          float v = acc[i][j][r];
          if constexpr (EPI == EPI_BIAS) v += bias[n];
          if constexpr (std::is_same_v<TC, u16>)
            C[(size_t)m * N + n] = f2b(v);
          else
            C[(size_t)m * N + n] = v;
        }
      }
    }
}

// ---------------------------------------------------------------------------
// fp32 -> bf16 casts for x, ctx, Wq, Wk, Wv in one 1-D launch.
// blocks: [0,16384) x, [16384,32768) ctx, then 3x1024 for the weights.
// ---------------------------------------------------------------------------
__global__ __launch_bounds__(256) void cast_all(
    const float* __restrict__ x, const float* __restrict__ ctx,
    const float* __restrict__ wq, const float* __restrict__ wk,
    const float* __restrict__ wv, u16* __restrict__ xb, u16* __restrict__ cb,
    u16* __restrict__ wqb, u16* __restrict__ wkb, u16* __restrict__ wvb) {
  int b = blockIdx.x;
  const float* s;
  u16* d;
  size_t off;
  if (b < 16384) { s = x; d = xb; off = b; }
  else if (b < 32768) { s = ctx; d = cb; off = b - 32768 + 16384; }
  else if (b < 33792) { s = wq; d = wqb; off = b - 32768; }
  else if (b < 34816) { s = wk; d = wkb; off = b - 33792; }
  else { s = wv; d = wvb; off = b - 34816; }
  const size_t i = (off * 256 + threadIdx.x) * 4;
  float4 v = *(const float4*)&s[i];
  ushort4 h;
  h.x = f2b(v.x); h.y = f2b(v.y); h.z = f2b(v.z); h.w = f2b(v.w);
  *(ushort4*)&d[i] = h;
}

// ---------------------------------------------------------------------------
// Row softmax over att [16384][2048]: reads RAW logits (fp32), applies
// scale + pad-mask (-1e9), softmax, writes fp32 att in place + bf16 copy.
// Fully-masked rows -> all -1e9 -> exp(0)=1 each -> uniform (matches ref).
// ---------------------------------------------------------------------------
__device__ __forceinline__ float blockReduceMax(float v, float* red) {
#pragma unroll
  for (int o = 32; o > 0; o >>= 1) v = fmaxf(v, __shfl_down(v, o));
  int t = threadIdx.x;
  if ((t & 63) == 0) red[t >> 6] = v;
  __syncthreads();
  float r = fmaxf(fmaxf(red[0], red[1]), fmaxf(red[2], red[3]));
  __syncthreads();
  return r;
}

__device__ __forceinline__ float blockReduceSum(float v, float* red) {
#pragma unroll
  for (int o = 32; o > 0; o >>= 1) v += __shfl_down(v, o);
  int t = threadIdx.x;
  if ((t & 63) == 0) red[t >> 6] = v;
  __syncthreads();
  float r = red[0] + red[1] + red[2] + red[3];
  __syncthreads();
  return r;
}

__global__ __launch_bounds__(256) void softmax_rows(float* __restrict__ att,
                                                    u16* __restrict__ attb,
                                                    const int* __restrict__ msk,
                                                    float scale) {
  __shared__ float red[4];
  float* p = att + (size_t)blockIdx.x * 2048;
  const int* mr = msk + (size_t)blockIdx.x * 2048;
  u16* pb = attb + (size_t)blockIdx.x * 2048;
  const int t = threadIdx.x;
  float4 v0 = ((const float4*)p)[t];
  float4 v1 = ((const float4*)p)[t + 256];
  int4 q0 = ((const int4*)mr)[t];
  int4 q1 = ((const int4*)mr)[t + 256];
  v0.x = q0.x ? -1e9f : v0.x * scale;
  v0.y = q0.y ? -1e9f : v0.y * scale;
  v0.z = q0.z ? -1e9f : v0.z * scale;
  v0.w = q0.w ? -1e9f : v0.w * scale;
  v1.x = q1.x ? -1e9f : v1.x * scale;
  v1.y = q1.y ? -1e9f : v1.y * scale;
  v1.z = q1.z ? -1e9f : v1.z * scale;
  v1.w = q1.w ? -1e9f : v1.w * scale;
  float mx = fmaxf(fmaxf(fmaxf(v0.x, v0.y), fmaxf(v0.z, v0.w)),
                   fmaxf(fmaxf(v1.x, v1.y), fmaxf(v1.z, v1.w)));
  mx = blockReduceMax(mx, red);
  float4 e0, e1;
  e0.x = __expf(v0.x - mx); e0.y = __expf(v0.y - mx);
  e0.z = __expf(v0.z - mx); e0.w = __expf(v0.w - mx);
  e1.x = __expf(v1.x - mx); e1.y = __expf(v1.y - mx);
  e1.z = __expf(v1.z - mx); e1.w = __expf(v1.w - mx);
  float s = (e0.x + e0.y + e0.z + e0.w) + (e1.x + e1.y + e1.z + e1.w);
  s = blockReduceSum(s, red);
  float inv = 1.0f / s;
  e0.x *= inv; e0.y *= inv; e0.z *= inv; e0.w *= inv;
  e1.x *= inv; e1.y *= inv; e1.z *= inv; e1.w *= inv;
  ((float4*)p)[t] = e0;
  ((float4*)p)[t + 256] = e1;
  ushort4 h0, h1;
  h0.x = f2b(e0.x); h0.y = f2b(e0.y); h0.z = f2b(e0.z); h0.w = f2b(e0.w);
  h1.x = f2b(e1.x); h1.y = f2b(e1.y); h1.z = f2b(e1.z); h1.w = f2b(e1.w);
  *(ushort4*)&pb[(size_t)t * 4] = h0;
  *(ushort4*)&pb[(size_t)(t + 256) * 4] = h1;
}

// ---------------------------------------------------------------------------
extern "C" void kernel_launch(void* const* d_in, const int* in_sizes, int n_in,
                              void* d_out, int out_size, void* d_ws,
                              size_t ws_size, hipStream_t stream) {
  const float* x   = (const float*)d_in[0];  // [8,2048,1024]
  const float* ctx = (const float*)d_in[1];  // [8,2048,1024]
  const int*   msk = (const int*)d_in[2];    // [8,2048,2048]
  const float* Wq  = (const float*)d_in[3];  // [1024,1024] == B^T layout
  const float* bq  = (const float*)d_in[4];
  const float* Wk  = (const float*)d_in[5];
  const float* bk  = (const float*)d_in[6];
  const float* Wv  = (const float*)d_in[7];
  const float* bv  = (const float*)d_in[8];

  float* out = (float*)d_out;   // 8*2048*1024
  float* att = out + 16777216;  // 8*2048*2048

  // ws (134 MB): xb | cb | Q | Kb.  Aliases: Vt<-xb (dead after Q proj),
  // attb<-Q+Kb (dead after QK^T).
  u16* xb = (u16*)d_ws;
  u16* cb = xb + 16777216;
  u16* Q  = cb + 16777216;
  u16* Kb = Q + 16777216;
  u16* Vt = xb;
  u16* attb = Q;
  // bf16 weights live in the att region of d_out; dead before QK^T writes it.
  u16* wqb = (u16*)att;
  u16* wkb = wqb + 1048576;
  u16* wvb = wkb + 1048576;

  dim3 blk(256), blkg(512);
  const long long SQ = 2048LL * 1024, SS = 2048LL * 2048, SV = 1024LL * 2048;

  cast_all<<<dim3(35840), blk, 0, stream>>>(x, ctx, Wq, Wk, Wv, xb, cb, wqb,
                                            wkb, wvb);

  // projections: M=16384, N=1024, K=1024 (Q first: V overwrites xb region)
  gemm_bt<u16, EPI_BIAS><<<dim3(4, 64, 1), blkg, 0, stream>>>(
      xb, wqb, Q, bq, 0.f, 1024, 1024, 0, 0, 0);
  gemm_bt<u16, EPI_BIAS><<<dim3(4, 64, 1), blkg, 0, stream>>>(
      cb, wkb, Kb, bk, 0.f, 1024, 1024, 0, 0, 0);
  gemm_bt<u16, EPI_BIAS_T><<<dim3(4, 64, 1), blkg, 0, stream>>>(
      cb, wvb, Vt, bv, 0.f, 1024, 1024, 0, 0, 0);

  // logits = Q K^T (RAW, fp32) -> att; scale+mask applied in softmax_rows
  gemm_bt<float, EPI_NONE><<<dim3(8, 8, 8), blkg, 0, stream>>>(
      Q, Kb, att, nullptr, 0.f, 2048, 1024, SQ, SQ, SS);

  softmax_rows<<<dim3(16384), blk, 0, stream>>>(att, attb, msk, 0.03125f);

  // out = att @ V : A=attb bf16, Bt=Vt bf16
  gemm_bt<float, EPI_NONE><<<dim3(4, 8, 8), blkg, 0, stream>>>(
      attb, Vt, out, nullptr, 0.f, 1024, 2048, SS, SV, SQ);
}

// Round 4
// 668.619 us; speedup vs baseline: 1.1696x; 1.0204x over previous
//
#include <hip/hip_runtime.h>
#include <hip/hip_bf16.h>
#include <type_traits>

typedef __attribute__((ext_vector_type(8))) __bf16 bf16x8;
typedef __attribute__((ext_vector_type(4))) float f32x4;
typedef unsigned short u16;

__device__ __forceinline__ u16 f2b(float x) {
  union { __hip_bfloat16 b; u16 u; } cv;
  cv.b = __float2bfloat16(x);
  return cv.u;
}

// async global->LDS, 16 B per lane. LDS dst = wave-uniform base + lane*16.
__device__ __forceinline__ void ld16(const u16* g, u16* l) {
  __builtin_amdgcn_global_load_lds(
      (const __attribute__((address_space(1))) unsigned int*)g,
      (__attribute__((address_space(3))) unsigned int*)l, 16, 0, 0);
}

// 256x256 tile, BK=64, 512 threads = 8 waves (2M x 4N), 128x64 out per wave.
// LDS: 2 x (A 32KB + B 32KB) = 128KB double buffer -> 1 block/CU, 2 waves/SIMD.
// Swizzle (verified, SQ_LDS_BANK_CONFLICT=0): row r stores global 16B-chunk
// c at slot c^(r&7); staging permutes the per-lane GLOBAL source column since
// global_load_lds pins LDS dst to base + lane*16. Read back with the same XOR.
//
// Tile body (2 barriers/tile, staging overlapped with MFMA):
//   entry: vmcnt(8) -> s_barrier          => S(kt) visible block-wide
//   phase A: 16 ds_read (A rows 0-63 + ALL B) -> 32 MFMA
//   8 ds_read (A rows 64-127) -> lgkmcnt(0) -> s_barrier  => buf b free
//   STAGE(kt+2 -> buf b) issue            => overlaps the next 32 MFMA
//   phase B: 32 MFMA
// B frags are loaded once per tile (bF[4][2]) -> 24 b128/tile/wave (was 28).
constexpr int BM = 256, BN = 256, BK = 64;

enum { EPI_NONE = 0, EPI_BIAS = 1, EPI_BIAS_T = 2 };

// C[m,n] = sum_k A[m,k] * Bt[n,k] (+ epilogue). A,Bt bf16.
// EPI_BIAS_T: C = Vt [8][1024][2048] bf16, written transposed (seq=2048).
// bias2: EPI_BIAS with gridDim.z==2 selects bias (z=0) / bias2 (z=1) --
// used to fuse the Q and K projections into one dispatch via the z-strides.
template <typename TC, int EPI>
__global__ __launch_bounds__(512, 2) void gemm_bt(
    const u16* __restrict__ A, const u16* __restrict__ Bt, TC* __restrict__ C,
    const float* __restrict__ bias, const float* __restrict__ bias2, int N,
    int K, long long sA, long long sB, long long sC) {
  __shared__ u16 As[2][BM * BK];  // 2 x 32 KB
  __shared__ u16 Bs[2][BN * BK];  // 2 x 32 KB

  // XCD-aware chunked remap (T1): hardware flat id i runs on XCD i%8; give
  // each XCD a contiguous x-fastest chunk. All grids here have nwg % 8 == 0.
  const int gx = gridDim.x, gy = gridDim.y;
  const int nwg = gx * gy * gridDim.z;
  int flat = (blockIdx.z * gy + blockIdx.y) * gx + blockIdx.x;
  flat = (flat & 7) * (nwg >> 3) + (flat >> 3);
  const int bx = flat % gx;
  const int rem = flat / gx;
  const int by = rem % gy;
  const int bz = rem / gy;

  A += (size_t)bz * sA;
  Bt += (size_t)bz * sB;
  C += (size_t)bz * sC;
  const float* bsel = (bz == 0) ? bias : bias2;

  const int m0 = by * BM, n0 = bx * BN;
  const int t = threadIdx.x, wave = t >> 6, lane = t & 63;
  const int wr = wave >> 2, wc = wave & 3;          // wave -> (M half, N quarter)
  const int fr = lane & 15, quad = lane >> 4;       // MFMA fragment coords
  const int lr = lane >> 3, lc = lane & 7;          // staging coords

  // staging: wave w, issue i covers rows i*64 + w*8 + lr; source col chunk
  // pre-swizzled (lc^lr) so linear LDS dst realizes slot = chunk ^ (row&7).
  const u16* ga = A + (size_t)(m0 + wave * 8 + lr) * K + (lc ^ lr) * 8;
  const u16* gb = Bt + (size_t)(n0 + wave * 8 + lr) * K + (lc ^ lr) * 8;

  f32x4 acc[8][4] = {};
  bf16x8 aF[4][2], bF[4][2];

  const int nt = K / BK;

  auto STAGE = [&](int kt, int bsel2) {
    const size_t ko = (size_t)kt * BK;
#pragma unroll
    for (int i = 0; i < 4; ++i) {
      ld16(ga + (size_t)(i * 64) * K + ko,
           &As[bsel2][(i * 64 + wave * 8) * BK]);
      ld16(gb + (size_t)(i * 64) * K + ko,
           &Bs[bsel2][(i * 64 + wave * 8) * BK]);
    }
  };

  // depth-2 prologue: 16 loads/thread in flight.
  STAGE(0, 0);
  STAGE(1, 1);

  for (int kt = 0; kt < nt; ++kt) {
    const int b = kt & 1;
    // counted wait: outstanding newer loads = S(kt+1)'s 8 -> vmcnt(8) lands
    // S(kt). Only the final tile (nothing newer in flight) drains to 0.
    if (kt + 1 < nt)
      __builtin_amdgcn_s_waitcnt(0x0f78);  // vmcnt(8)
    else
      __builtin_amdgcn_s_waitcnt(0x0f70);  // vmcnt(0)
    __builtin_amdgcn_s_barrier();          // S(kt) visible block-wide
    __builtin_amdgcn_sched_barrier(0);     // keep tile reads below the barrier

    // ---- phase A: A row-groups 0-3 (wave rows 0-63) + ALL B frags ----
#pragma unroll
    for (int i = 0; i < 4; ++i)
#pragma unroll
      for (int ks = 0; ks < 2; ++ks)
        aF[i][ks] = *(const bf16x8*)&As[b][
            (wr * 128 + i * 16 + fr) * BK + (((ks * 4 + quad) ^ (fr & 7)) * 8)];
#pragma unroll
    for (int j = 0; j < 4; ++j)
#pragma unroll
      for (int ks = 0; ks < 2; ++ks)
        bF[j][ks] = *(const bf16x8*)&Bs[b][
            (wc * 64 + j * 16 + fr) * BK + (((ks * 4 + quad) ^ (fr & 7)) * 8)];
#pragma unroll
    for (int i = 0; i < 4; ++i)
#pragma unroll
      for (int j = 0; j < 4; ++j)
#pragma unroll
        for (int ks = 0; ks < 2; ++ks)
          acc[i][j] = __builtin_amdgcn_mfma_f32_16x16x32_bf16(
              aF[i][ks], bF[j][ks], acc[i][j], 0, 0, 0);

    // ---- phase B reads: A row-groups 4-7 (wave rows 64-127) ----
#pragma unroll
    for (int i = 0; i < 4; ++i)
#pragma unroll
      for (int ks = 0; ks < 2; ++ks)
        aF[i][ks] = *(const bf16x8*)&As[b][
            (wr * 128 + 64 + i * 16 + fr) * BK +
            (((ks * 4 + quad) ^ (fr & 7)) * 8)];
    __builtin_amdgcn_s_waitcnt(0xc07f);    // lgkmcnt(0): reads of buf b done
    __builtin_amdgcn_sched_barrier(0);     // pin reads above the barrier
    __builtin_amdgcn_s_barrier();          // block-wide: buf b is free
    __builtin_amdgcn_sched_barrier(0);     // pin STAGE below the barrier
    if (kt + 2 < nt) STAGE(kt + 2, b);     // issue overlaps phase-B MFMAs

    // ---- phase B: 32 MFMA (B frags reused) ----
#pragma unroll
    for (int i = 0; i < 4; ++i)
#pragma unroll
      for (int j = 0; j < 4; ++j)
#pragma unroll
        for (int ks = 0; ks < 2; ++ks)
          acc[i + 4][j] = __builtin_amdgcn_mfma_f32_16x16x32_bf16(
              aF[i][ks], bF[j][ks], acc[i + 4][j], 0, 0, 0);
  }

  // C/D layout: col = lane&15 (fr), row = quad*4 + reg
#pragma unroll
  for (int i = 0; i < 8; ++i)
#pragma unroll
    for (int j = 0; j < 4; ++j) {
      const int mb = m0 + wr * 128 + i * 16 + quad * 4;
      const int n = n0 + wc * 64 + j * 16 + fr;
      if constexpr (EPI == EPI_BIAS_T) {
        const float bb = bsel[n];
        const int bb2 = mb >> 11, ml = mb & 2047;  // seq = 2048 per batch
        ushort4 o;
        o.x = f2b(acc[i][j][0] + bb);
        o.y = f2b(acc[i][j][1] + bb);
        o.z = f2b(acc[i][j][2] + bb);
        o.w = f2b(acc[i][j][3] + bb);
        *(ushort4*)&((u16*)C)[(size_t)bb2 * 2097152 + (size_t)n * 2048 + ml] =
            o;
      } else {
#pragma unroll
        for (int r = 0; r < 4; ++r) {
          const int m = mb + r;
          float v = acc[i][j][r];
          if constexpr (EPI == EPI_BIAS) v += bsel[n];
          if constexpr (std::is_same_v<TC, u16>)
            C[(size_t)m * N + n] = f2b(v);
          else
            C[(size_t)m * N + n] = v;
        }
      }
    }
}

// ---------------------------------------------------------------------------
// fp32 -> bf16 casts for x, ctx, Wq, Wk, Wv in one 1-D launch.
// blocks: [0,16384) x, [16384,32768) ctx, then 3x1024 for the weights.
// ---------------------------------------------------------------------------
__global__ __launch_bounds__(256) void cast_all(
    const float* __restrict__ x, const float* __restrict__ ctx,
    const float* __restrict__ wq, const float* __restrict__ wk,
    const float* __restrict__ wv, u16* __restrict__ xb, u16* __restrict__ cb,
    u16* __restrict__ wqb, u16* __restrict__ wkb, u16* __restrict__ wvb) {
  int b = blockIdx.x;
  const float* s;
  u16* d;
  size_t off;
  if (b < 16384) { s = x; d = xb; off = b; }
  else if (b < 32768) { s = ctx; d = cb; off = b - 32768 + 16384; }
  else if (b < 33792) { s = wq; d = wqb; off = b - 32768; }
  else if (b < 34816) { s = wk; d = wkb; off = b - 33792; }
  else { s = wv; d = wvb; off = b - 34816; }
  const size_t i = (off * 256 + threadIdx.x) * 4;
  float4 v = *(const float4*)&s[i];
  ushort4 h;
  h.x = f2b(v.x); h.y = f2b(v.y); h.z = f2b(v.z); h.w = f2b(v.w);
  *(ushort4*)&d[i] = h;
}

// ---------------------------------------------------------------------------
// Row softmax over att [16384][2048]: reads RAW logits (fp32), applies
// scale + pad-mask (-1e9), softmax, writes fp32 att in place + bf16 copy.
// Fully-masked rows -> all -1e9 -> exp(0)=1 each -> uniform (matches ref).
// ---------------------------------------------------------------------------
__device__ __forceinline__ float blockReduceMax(float v, float* red) {
#pragma unroll
  for (int o = 32; o > 0; o >>= 1) v = fmaxf(v, __shfl_down(v, o));
  int t = threadIdx.x;
  if ((t & 63) == 0) red[t >> 6] = v;
  __syncthreads();
  float r = fmaxf(fmaxf(red[0], red[1]), fmaxf(red[2], red[3]));
  __syncthreads();
  return r;
}

__device__ __forceinline__ float blockReduceSum(float v, float* red) {
#pragma unroll
  for (int o = 32; o > 0; o >>= 1) v += __shfl_down(v, o);
  int t = threadIdx.x;
  if ((t & 63) == 0) red[t >> 6] = v;
  __syncthreads();
  float r = red[0] + red[1] + red[2] + red[3];
  __syncthreads();
  return r;
}

__global__ __launch_bounds__(256) void softmax_rows(float* __restrict__ att,
                                                    u16* __restrict__ attb,
                                                    const int* __restrict__ msk,
                                                    float scale) {
  __shared__ float red[4];
  float* p = att + (size_t)blockIdx.x * 2048;
  const int* mr = msk + (size_t)blockIdx.x * 2048;
  u16* pb = attb + (size_t)blockIdx.x * 2048;
  const int t = threadIdx.x;
  float4 v0 = ((const float4*)p)[t];
  float4 v1 = ((const float4*)p)[t + 256];
  int4 q0 = ((const int4*)mr)[t];
  int4 q1 = ((const int4*)mr)[t + 256];
  v0.x = q0.x ? -1e9f : v0.x * scale;
  v0.y = q0.y ? -1e9f : v0.y * scale;
  v0.z = q0.z ? -1e9f : v0.z * scale;
  v0.w = q0.w ? -1e9f : v0.w * scale;
  v1.x = q1.x ? -1e9f : v1.x * scale;
  v1.y = q1.y ? -1e9f : v1.y * scale;
  v1.z = q1.z ? -1e9f : v1.z * scale;
  v1.w = q1.w ? -1e9f : v1.w * scale;
  float mx = fmaxf(fmaxf(fmaxf(v0.x, v0.y), fmaxf(v0.z, v0.w)),
                   fmaxf(fmaxf(v1.x, v1.y), fmaxf(v1.z, v1.w)));
  mx = blockReduceMax(mx, red);
  float4 e0, e1;
  e0.x = __expf(v0.x - mx); e0.y = __expf(v0.y - mx);
  e0.z = __expf(v0.z - mx); e0.w = __expf(v0.w - mx);
  e1.x = __expf(v1.x - mx); e1.y = __expf(v1.y - mx);
  e1.z = __expf(v1.z - mx); e1.w = __expf(v1.w - mx);
  float s = (e0.x + e0.y + e0.z + e0.w) + (e1.x + e1.y + e1.z + e1.w);
  s = blockReduceSum(s, red);
  float inv = 1.0f / s;
  e0.x *= inv; e0.y *= inv; e0.z *= inv; e0.w *= inv;
  e1.x *= inv; e1.y *= inv; e1.z *= inv; e1.w *= inv;
  ((float4*)p)[t] = e0;
  ((float4*)p)[t + 256] = e1;
  ushort4 h0, h1;
  h0.x = f2b(e0.x); h0.y = f2b(e0.y); h0.z = f2b(e0.z); h0.w = f2b(e0.w);
  h1.x = f2b(e1.x); h1.y = f2b(e1.y); h1.z = f2b(e1.z); h1.w = f2b(e1.w);
  *(ushort4*)&pb[(size_t)t * 4] = h0;
  *(ushort4*)&pb[(size_t)(t + 256) * 4] = h1;
}

// ---------------------------------------------------------------------------
extern "C" void kernel_launch(void* const* d_in, const int* in_sizes, int n_in,
                              void* d_out, int out_size, void* d_ws,
                              size_t ws_size, hipStream_t stream) {
  const float* x   = (const float*)d_in[0];  // [8,2048,1024]
  const float* ctx = (const float*)d_in[1];  // [8,2048,1024]
  const int*   msk = (const int*)d_in[2];    // [8,2048,2048]
  const float* Wq  = (const float*)d_in[3];  // [1024,1024] == B^T layout
  const float* bq  = (const float*)d_in[4];
  const float* Wk  = (const float*)d_in[5];
  const float* bk  = (const float*)d_in[6];
  const float* Wv  = (const float*)d_in[7];
  const float* bv  = (const float*)d_in[8];

  float* out = (float*)d_out;   // 8*2048*1024
  float* att = out + 16777216;  // 8*2048*2048

  // ws (134 MB): xb | cb | Q | Kb.  Aliases: Vt<-xb (dead after Q proj),
  // attb<-Q+Kb (dead after QK^T).
  u16* xb = (u16*)d_ws;
  u16* cb = xb + 16777216;
  u16* Q  = cb + 16777216;
  u16* Kb = Q + 16777216;
  u16* Vt = xb;
  u16* attb = Q;
  // bf16 weights live in the att region of d_out; dead before QK^T writes it.
  u16* wqb = (u16*)att;
  u16* wkb = wqb + 1048576;
  u16* wvb = wkb + 1048576;

  dim3 blk(256), blkg(512);
  const long long SQ = 2048LL * 1024, SS = 2048LL * 2048, SV = 1024LL * 2048;

  cast_all<<<dim3(35840), blk, 0, stream>>>(x, ctx, Wq, Wk, Wv, xb, cb, wqb,
                                            wkb, wvb);

  // Q + K projections fused via z (xb/cb, wqb/wkb, Q/Kb are equidistant):
  // M=16384, N=1024, K=1024.  Must precede V (V overwrites xb region).
  gemm_bt<u16, EPI_BIAS><<<dim3(4, 64, 2), blkg, 0, stream>>>(
      xb, wqb, Q, bq, bk, 1024, 1024, 16777216LL, 1048576LL, 16777216LL);
  gemm_bt<u16, EPI_BIAS_T><<<dim3(4, 64, 1), blkg, 0, stream>>>(
      cb, wvb, Vt, bv, bv, 1024, 1024, 0, 0, 0);

  // logits = Q K^T (RAW, fp32) -> att; scale+mask applied in softmax_rows
  gemm_bt<float, EPI_NONE><<<dim3(8, 8, 8), blkg, 0, stream>>>(
      Q, Kb, att, nullptr, nullptr, 2048, 1024, SQ, SQ, SS);

  softmax_rows<<<dim3(16384), blk, 0, stream>>>(att, attb, msk, 0.03125f);

  // out = att @ V : A=attb bf16, Bt=Vt bf16
  gemm_bt<float, EPI_NONE><<<dim3(4, 8, 8), blkg, 0, stream>>>(
      attb, Vt, out, nullptr, nullptr, 1024, 2048, SS, SV, SQ);
}